// Round 1
// baseline (248.689 us; speedup 1.0000x reference)
//
#include <hip/hip_runtime.h>

#define NB 4
#define HWN 4096
#define CD 64

typedef short short8 __attribute__((ext_vector_type(8), may_alias));
typedef float f32x4 __attribute__((ext_vector_type(4), may_alias));

__device__ constexpr float C1 = 0.18033688011112042f; // log2(e)/8

__device__ __forceinline__ unsigned short f2bf(float f) {
    unsigned u = __builtin_bit_cast(unsigned, f);
    u = (u + 0x7FFFu + ((u >> 16) & 1u)) >> 16;  // RTN-even
    return (unsigned short)u;
}

__device__ __forceinline__ float fexp2(float x) {
#if __has_builtin(__builtin_amdgcn_exp2f)
    return __builtin_amdgcn_exp2f(x);
#else
    return exp2f(x);
#endif
}

// ---------- prep: Q,K fp32 -> bf16 ----------
__global__ __launch_bounds__(256) void cvt_qk(const float* __restrict__ Q,
                                              const float* __restrict__ K,
                                              unsigned short* __restrict__ Qb,
                                              unsigned short* __restrict__ Kb) {
    int i = (blockIdx.x * 256 + threadIdx.x) * 4;  // total NB*HWN*CD = 1M, grid 1024
    float4 q = *(const float4*)(Q + i);
    float4 k = *(const float4*)(K + i);
    ushort4 qo, ko;
    qo.x = f2bf(q.x); qo.y = f2bf(q.y); qo.z = f2bf(q.z); qo.w = f2bf(q.w);
    ko.x = f2bf(k.x); ko.y = f2bf(k.y); ko.z = f2bf(k.z); ko.w = f2bf(k.w);
    *(ushort4*)(Qb + i) = qo;
    *(ushort4*)(Kb + i) = ko;
}

// ---------- phase 1: l[n,k] = sum_q exp2(C1 * dot(Q[q],K[k])) ----------
// S^T tiles: A = K (m = key), B = Q (n-dim = query). C/D: col=lane&15 (q), row=quad*4+r (key)
__global__ __launch_bounds__(256) void lsum_kernel(const unsigned short* __restrict__ Qb,
                                                   const unsigned short* __restrict__ Kb,
                                                   float* __restrict__ l) {
    int tid = threadIdx.x;
    int w = tid >> 6, lane = tid & 63, quad = lane >> 4, m16 = lane & 15;
    int n = blockIdx.y;
    int kbase = blockIdx.x * 64 + w * 16;

    const unsigned short* Kp = Kb + ((size_t)(n * HWN + kbase + m16)) * CD + quad * 8;
    short8 kf0 = *(const short8*)(Kp);
    short8 kf1 = *(const short8*)(Kp + 32);

    const unsigned short* Qp = Qb + ((size_t)(n * HWN + blockIdx.z * 2048 + m16)) * CD + quad * 8;

    float l0 = 0.f, l1 = 0.f, l2 = 0.f, l3 = 0.f;
    for (int qc = 0; qc < 128; ++qc) {
        short8 qf0 = *(const short8*)(Qp);
        short8 qf1 = *(const short8*)(Qp + 32);
        f32x4 acc = {0.f, 0.f, 0.f, 0.f};
        acc = __builtin_amdgcn_mfma_f32_16x16x32_bf16(kf0, qf0, acc, 0, 0, 0);
        acc = __builtin_amdgcn_mfma_f32_16x16x32_bf16(kf1, qf1, acc, 0, 0, 0);
        l0 += fexp2(acc[0] * C1);
        l1 += fexp2(acc[1] * C1);
        l2 += fexp2(acc[2] * C1);
        l3 += fexp2(acc[3] * C1);
        Qp += 16 * CD;
    }
    // reduce across the 16 lanes of each quad (cols = q)
    for (int d = 1; d < 16; d <<= 1) {
        l0 += __shfl_xor(l0, d);
        l1 += __shfl_xor(l1, d);
        l2 += __shfl_xor(l2, d);
        l3 += __shfl_xor(l3, d);
    }
    if (m16 == 0) {
        float* lp = l + n * HWN + kbase + quad * 4;
        atomicAdd(lp + 0, l0);
        atomicAdd(lp + 1, l1);
        atomicAdd(lp + 2, l2);
        atomicAdd(lp + 3, l3);
    }
}

// ---------- prep: Vt[n][c][k] = bf16(V[n][k][c] / l[n][k]) ----------
__global__ __launch_bounds__(256) void prep_v(const float* __restrict__ V,
                                              const float* __restrict__ l,
                                              unsigned short* __restrict__ Vt) {
    __shared__ float rl[64];
    __shared__ float tile[64][65];
    int tid = threadIdx.x, n = blockIdx.y, kbase = blockIdx.x * 64;
    if (tid < 64) rl[tid] = 1.0f / l[n * HWN + kbase + tid];
    __syncthreads();
#pragma unroll
    for (int i = 0; i < 16; ++i) {
        int e = i * 256 + tid;
        int k = e >> 6, c = e & 63;
        tile[c][k] = V[((size_t)(n * HWN + kbase + k)) * CD + c] * rl[k];
    }
    __syncthreads();
#pragma unroll
    for (int i = 0; i < 16; ++i) {
        int e = i * 256 + tid;
        int c = e >> 6, kk = e & 63;
        Vt[((size_t)(n * CD + c)) * HWN + kbase + kk] = f2bf(tile[c][kk]);
    }
}

// ---------- phase 2: out[q,c] = sum_k exp2(C1*s_qk) * Vt[c][k] ----------
__global__ __launch_bounds__(256) void attn_kernel(const unsigned short* __restrict__ Qb,
                                                   const unsigned short* __restrict__ Kb,
                                                   const unsigned short* __restrict__ Vt,
                                                   float* __restrict__ out) {
    // per-wave P buffer: 16 q rows x 32 k cols, row stride 40 bf16 (80B, 16B-aligned, bank-spread)
    __shared__ short plds[4][16][40];
    int tid = threadIdx.x;
    int w = tid >> 6, lane = tid & 63, quad = lane >> 4, m16 = lane & 15;
    int n = blockIdx.y;
    int qbase = blockIdx.x * 64 + w * 16;
    int kb0 = blockIdx.z * 2048;

    const unsigned short* Qp = Qb + ((size_t)(n * HWN + qbase + m16)) * CD + quad * 8;
    short8 qf0 = *(const short8*)(Qp);
    short8 qf1 = *(const short8*)(Qp + 32);

    const unsigned short* Kp = Kb + ((size_t)(n * HWN + kb0 + m16)) * CD + quad * 8;
    const unsigned short* Vp = Vt + ((size_t)(n * CD + m16)) * HWN + kb0 + quad * 8;

    f32x4 o[4];
#pragma unroll
    for (int ct = 0; ct < 4; ++ct) o[ct] = f32x4{0.f, 0.f, 0.f, 0.f};

    short* pw = &plds[w][0][0];

    for (int kc = 0; kc < 64; ++kc) {
        // S tile: 16q x 32k  (A = Q, B = K)
        short8 kf00 = *(const short8*)(Kp);
        short8 kf01 = *(const short8*)(Kp + 32);
        short8 kf10 = *(const short8*)(Kp + 16 * CD);
        short8 kf11 = *(const short8*)(Kp + 16 * CD + 32);
        f32x4 s0 = {0.f, 0.f, 0.f, 0.f}, s1 = {0.f, 0.f, 0.f, 0.f};
        s0 = __builtin_amdgcn_mfma_f32_16x16x32_bf16(qf0, kf00, s0, 0, 0, 0);
        s0 = __builtin_amdgcn_mfma_f32_16x16x32_bf16(qf1, kf01, s0, 0, 0, 0);
        s1 = __builtin_amdgcn_mfma_f32_16x16x32_bf16(qf0, kf10, s1, 0, 0, 0);
        s1 = __builtin_amdgcn_mfma_f32_16x16x32_bf16(qf1, kf11, s1, 0, 0, 0);

        // P = exp2(C1*s), C-layout -> LDS (row = quad*4+r, col = t*16+m16)
        short* prow = pw + (quad * 4) * 40 + m16;
#pragma unroll
        for (int r = 0; r < 4; ++r) {
            prow[r * 40]      = (short)f2bf(fexp2(s0[r] * C1));
            prow[r * 40 + 16] = (short)f2bf(fexp2(s1[r] * C1));
        }
        // A-layout read: row = m16, k = quad*8..quad*8+7 (in-order per-wave DS, no barrier)
        short8 pf = *(const short8*)(pw + m16 * 40 + quad * 8);

#pragma unroll
        for (int ct = 0; ct < 4; ++ct) {
            short8 vf = *(const short8*)(Vp + (size_t)ct * 16 * HWN);
            o[ct] = __builtin_amdgcn_mfma_f32_16x16x32_bf16(pf, vf, o[ct], 0, 0, 0);
        }
        Kp += 32 * CD;
        Vp += 32;
    }

    float* op = out + ((size_t)(n * HWN + qbase + quad * 4)) * CD + m16;
#pragma unroll
    for (int ct = 0; ct < 4; ++ct)
#pragma unroll
        for (int r = 0; r < 4; ++r)
            atomicAdd(op + r * CD + ct * 16, o[ct][r]);
}

extern "C" void kernel_launch(void* const* d_in, const int* in_sizes, int n_in,
                              void* d_out, int out_size, void* d_ws, size_t ws_size,
                              hipStream_t stream) {
    const float* Q = (const float*)d_in[0];
    const float* K = (const float*)d_in[1];
    const float* V = (const float*)d_in[2];
    float* out = (float*)d_out;

    char* ws = (char*)d_ws;
    unsigned short* Qb = (unsigned short*)(ws);                    // 2 MB
    unsigned short* Kb = (unsigned short*)(ws + (1u << 21));       // 2 MB
    unsigned short* Vt = (unsigned short*)(ws + (2u << 21));       // 2 MB
    float* l          = (float*)(ws + (3u << 21));                 // 64 KB

    hipMemsetAsync(out, 0, (size_t)NB * HWN * CD * sizeof(float), stream);
    hipMemsetAsync(l, 0, (size_t)NB * HWN * sizeof(float), stream);

    cvt_qk<<<1024, 256, 0, stream>>>(Q, K, Qb, Kb);
    lsum_kernel<<<dim3(64, 4, 2), 256, 0, stream>>>(Qb, Kb, l);
    prep_v<<<dim3(64, 4), 256, 0, stream>>>(V, l, Vt);
    attn_kernel<<<dim3(64, 4, 2), 256, 0, stream>>>(Qb, Kb, Vt, out);
}